// Round 12
// baseline (5326.805 us; speedup 1.0000x reference)
//
#include <hip/hip_runtime.h>
#include <cstddef>
#include <cstdint>

// ---------------------------------------------------------------------------
// GridNetBlock forward. B=2,T=512,QF=64,C=128,H=256,KD=4,NH=4,E=8,VD=32,L=100.
// Round 12: inter-LSTM v7 — 1024-thread WGs (16 waves x 4 nt = in-register
// gate quadruples), ping-pong h in LDS (1 barrier/step), bf16 xw stream.
// Workspace: 30,629,376 floats = 122.5 MiB.
// ---------------------------------------------------------------------------

#define EPSV 1e-5f

typedef __attribute__((ext_vector_type(8))) short bf16x8;
typedef __attribute__((ext_vector_type(4))) float f32x4;

// ---- workspace offsets (in float units) ----
#define O_WCBT  0           // 65536 u16: conv W^T rows o, cols k*128+c
#define O_WDBT  32768       // 262144 u16: deconv W^T rows o*4+k, cols c
#define O_WIHI  163840      // 131072 u16: Wih_i [1024][128]
#define O_WILB  229376      // 32768 u16: W_il [128][256]
#define O_WQKV  245760      // 24576 u16: rows 0-31 Wq, 32-63 Wk, 64-191 Wv
#define O_WPB   258048      // 16384 u16: Wp [128][128]
#define O_WFIF  266240      // 393216 u16: intra fwd frag [nt][ks12][lane][8]
#define O_WFIB  462848      // 393216 u16: intra bwd frag
#define O_WFII  659456      // 262144 u16: inter Whh frag [nt][ks8][lane][8]
#define O_BPF   790528      // 1024 fl: permuted bias intra fwd
#define O_BPB   791552      // 1024 fl: permuted bias intra bwd
#define O_BDE   792576      // 512 fl: deconv bias expanded
#define O_BSI   793088      // 1024 fl: bih_i+bhh_i (standard order, for GEMM)
#define O_HI    794112      // 32768 fl inter h state
#define O_CI    826880      // 32768 fl inter c state
#define O_ATTN  859648      // 409600 fl
#define O_PA    1269248     // 8,388,608 fl region A
#define O_PB    9657856     // 8,388,608 fl region B
#define O_PC    18046464    // 12,582,912 fl region C
// end 30,629,376 fl

static __device__ __forceinline__ float sigm(float x) { return 1.f / (1.f + __expf(-x)); }
static __device__ __forceinline__ float tanhfast(float x) { return 1.f - 2.f / (__expf(2.f * x) + 1.f); }
static __device__ __forceinline__ unsigned short f2bf(float f) {
  union { float f; uint32_t u; } v; v.f = f;
  uint32_t r = v.u + 0x7fffu + ((v.u >> 16) & 1u);
  return (unsigned short)(r >> 16);
}
static __device__ __forceinline__ float bf2f(unsigned short u) {
  union { uint32_t u; float f; } v; v.u = ((uint32_t)u) << 16;
  return v.f;
}
// permuted gate index: p = nt*16+j -> original gate (nt&3)*256 + (nt>>2)*16 + j
static __device__ __forceinline__ int gate_of(int nt, int j) {
  return (nt & 3) * 256 + ((nt >> 2) << 4) + j;
}

// ---------------------------------------------------------------------------
// weight prep (fp32 -> bf16 layouts + fragment swizzles + bias sums)
// ---------------------------------------------------------------------------
__global__ __launch_bounds__(256) void prep_weights(
    const float* __restrict__ Wc, const float* __restrict__ Wdec,
    const float* __restrict__ bdec,
    const float* __restrict__ Wih_i, const float* __restrict__ Wil,
    const float* __restrict__ Wq, const float* __restrict__ Wk,
    const float* __restrict__ Wv, const float* __restrict__ Wp,
    const float* __restrict__ Wih_f, const float* __restrict__ Whh_f,
    const float* __restrict__ Wih_b, const float* __restrict__ Whh_b,
    const float* __restrict__ Whh_i,
    const float* __restrict__ bih_f, const float* __restrict__ bhh_f,
    const float* __restrict__ bih_b, const float* __restrict__ bhh_b,
    const float* __restrict__ bih_i, const float* __restrict__ bhh_i,
    float* __restrict__ ws)
{
  int idx = blockIdx.x * 256 + threadIdx.x;
  if (idx < 65536) { // WcT_bt[o][k*128+c] = Wc[o][c][k]
    int o = idx >> 9, kc = idx & 511, k = kc >> 7, c = kc & 127;
    ((unsigned short*)(ws + O_WCBT))[idx] = f2bf(Wc[o * 512 + c * 4 + k]);
    return;
  }
  idx -= 65536;
  if (idx < 262144) { // Wd_bt[ok][c] = Wdec[c*512+ok]
    int ok = idx >> 9, c = idx & 511;
    ((unsigned short*)(ws + O_WDBT))[idx] = f2bf(Wdec[c * 512 + ok]);
    return;
  }
  idx -= 262144;
  if (idx < 131072) { ((unsigned short*)(ws + O_WIHI))[idx] = f2bf(Wih_i[idx]); return; }
  idx -= 131072;
  if (idx < 32768) { ((unsigned short*)(ws + O_WILB))[idx] = f2bf(Wil[idx]); return; }
  idx -= 32768;
  if (idx < 24576) { // Wqkv rows: 0-31 Wq, 32-63 Wk, 64-191 Wv
    int row = idx >> 7, c = idx & 127;
    float v = (row < 32) ? Wq[row * 128 + c]
            : (row < 64) ? Wk[(row - 32) * 128 + c]
                         : Wv[(row - 64) * 128 + c];
    ((unsigned short*)(ws + O_WQKV))[idx] = f2bf(v);
    return;
  }
  idx -= 24576;
  if (idx < 16384) { ((unsigned short*)(ws + O_WPB))[idx] = f2bf(Wp[idx]); return; }
  idx -= 16384;
  if (idx < 393216) { // intra fwd frag: [((nt*12+ks)*64+l)*8+e], K=384=[x|h]
    int e = idx & 7, l = (idx >> 3) & 63, t = idx >> 9;
    int ks = t % 12, nt = t / 12;
    int gate = gate_of(nt, l & 15);
    int k = ks * 32 + (l >> 4) * 8 + e;
    float v = (k < 128) ? Wih_f[gate * 128 + k] : Whh_f[gate * 256 + (k - 128)];
    ((unsigned short*)(ws + O_WFIF))[idx] = f2bf(v);
    return;
  }
  idx -= 393216;
  if (idx < 393216) { // intra bwd frag
    int e = idx & 7, l = (idx >> 3) & 63, t = idx >> 9;
    int ks = t % 12, nt = t / 12;
    int gate = gate_of(nt, l & 15);
    int k = ks * 32 + (l >> 4) * 8 + e;
    float v = (k < 128) ? Wih_b[gate * 128 + k] : Whh_b[gate * 256 + (k - 128)];
    ((unsigned short*)(ws + O_WFIB))[idx] = f2bf(v);
    return;
  }
  idx -= 393216;
  if (idx < 262144) { // inter Whh frag: [((nt*8+ks)*64+l)*8+e], K=256
    int e = idx & 7, l = (idx >> 3) & 63, t = idx >> 9;
    int ks = t & 7, nt = t >> 3;
    int gate = gate_of(nt, l & 15);
    int k = ks * 32 + (l >> 4) * 8 + e;
    ((unsigned short*)(ws + O_WFII))[idx] = f2bf(Whh_i[gate * 256 + k]);
    return;
  }
  idx -= 262144;
  if (idx < 512) { ws[O_BDE + idx] = bdec[idx >> 2]; return; }
  idx -= 512;
  if (idx < 1024) { // permuted intra fwd bias
    int gate = gate_of(idx >> 4, idx & 15);
    ws[O_BPF + idx] = bih_f[gate] + bhh_f[gate];
    return;
  }
  idx -= 1024;
  if (idx < 1024) {
    int gate = gate_of(idx >> 4, idx & 15);
    ws[O_BPB + idx] = bih_b[gate] + bhh_b[gate];
    return;
  }
  idx -= 1024;
  if (idx < 1024) { ws[O_BSI + idx] = bih_i[idx] + bhh_i[idx]; return; }
}

// fp32 -> bf16 cast, 4 elems/thread
__global__ __launch_bounds__(256) void cast_f2b(
    const float* __restrict__ in, unsigned short* __restrict__ out, int n4)
{
  int i = blockIdx.x * 256 + threadIdx.x;
  if (i >= n4) return;
  float4 v = ((const float4*)in)[i];
  ushort4 o;
  o.x = f2bf(v.x); o.y = f2bf(v.y); o.z = f2bf(v.z); o.w = f2bf(v.w);
  ((ushort4*)out)[i] = o;
}

// ---------------------------------------------------------------------------
// bf16 MFMA GEMM: C[M][N] = A[M][K] * Bt[N][K]^T (+bias[N]) (+prelu)
// Optional A-row remap for time-chunked GEMMs; optional bf16 output.
// ---------------------------------------------------------------------------
__global__ __launch_bounds__(256) void gemm_mfma(
    const unsigned short* __restrict__ A, const unsigned short* __restrict__ Bt,
    void* __restrict__ Cout, int M, int N, int K,
    const float* __restrict__ bias, const float* __restrict__ pa, int c_bf16,
    int a_chunk, int a_stride, int a_t0)
{
  __shared__ unsigned short As[128 * 72];
  __shared__ unsigned short Bs[128 * 72];
  const int bm = blockIdx.x * 128, bn = blockIdx.y * 128;
  const int tid = threadIdx.x, lane = tid & 63, wave = tid >> 6;
  const int wm = (wave >> 1) * 64, wn = (wave & 1) * 64;
  f32x4 acc[4][4];
#pragma unroll
  for (int i = 0; i < 4; ++i)
#pragma unroll
    for (int j = 0; j < 4; ++j)
#pragma unroll
      for (int e = 0; e < 4; ++e) acc[i][j][e] = 0.f;

  for (int k0 = 0; k0 < K; k0 += 64) {
#pragma unroll
    for (int it = 0; it < 4; ++it) {
      int ch = tid + it * 256;          // 0..1023
      int r = ch >> 3, kc = ch & 7;
      int arow = bm + r;
      if (a_chunk) arow = (arow / a_chunk) * a_stride + a_t0 + (arow % a_chunk);
      *(bf16x8*)&As[r * 72 + kc * 8] =
          *(const bf16x8*)(A + (size_t)arow * K + k0 + kc * 8);
      int nrow = bn + r; if (nrow > N - 1) nrow = N - 1;
      *(bf16x8*)&Bs[r * 72 + kc * 8] =
          *(const bf16x8*)(Bt + (size_t)nrow * K + k0 + kc * 8);
    }
    __syncthreads();
#pragma unroll
    for (int kk = 0; kk < 64; kk += 32) {
      const int kb = kk + (lane >> 4) * 8;
      bf16x8 af[4], bfr[4];
#pragma unroll
      for (int mb = 0; mb < 4; ++mb)
        af[mb] = *(const bf16x8*)&As[(wm + mb * 16 + (lane & 15)) * 72 + kb];
#pragma unroll
      for (int nb = 0; nb < 4; ++nb)
        bfr[nb] = *(const bf16x8*)&Bs[(wn + nb * 16 + (lane & 15)) * 72 + kb];
#pragma unroll
      for (int mb = 0; mb < 4; ++mb)
#pragma unroll
        for (int nb = 0; nb < 4; ++nb)
          acc[mb][nb] = __builtin_amdgcn_mfma_f32_16x16x32_bf16(
              af[mb], bfr[nb], acc[mb][nb], 0, 0, 0);
    }
    __syncthreads();
  }
  const float aval = pa ? pa[0] : 0.f;
#pragma unroll
  for (int mb = 0; mb < 4; ++mb) {
#pragma unroll
    for (int nb = 0; nb < 4; ++nb) {
      int col = bn + wn + nb * 16 + (lane & 15);
      if (col >= N) continue;
      float bv = bias ? bias[col] : 0.f;
#pragma unroll
      for (int i = 0; i < 4; ++i) {
        int row = bm + wm + mb * 16 + (lane >> 4) * 4 + i;
        float v = acc[mb][nb][i] + bv;
        if (pa) v = v >= 0.f ? v : aval * v;
        if (c_bf16) ((unsigned short*)Cout)[(size_t)row * N + col] = f2bf(v);
        else        ((float*)Cout)[(size_t)row * N + col] = v;
      }
    }
  }
}

// ---------------------------------------------------------------------------
// LayerNorm over last dim D; optional output row-perm; optional residual add;
// optional bf16 output.
// ---------------------------------------------------------------------------
__global__ __launch_bounds__(256) void ln_rows(
    const float* in, float* out, unsigned short* outb, int D,
    const float* __restrict__ g, const float* __restrict__ b,
    const float* addsrc, int permmode)
{
  const int row = blockIdx.x;
  size_t orow = row;
  if (permmode == 1) {
    int bb = row >> 15, t = (row >> 6) & 511, qf = row & 63;
    orow = (size_t)((bb << 6) | qf) * 512 + t;
  }
  const float* p = in + (size_t)row * D;
  float s = 0.f, s2 = 0.f;
  for (int i = threadIdx.x; i < D; i += 256) { float v = p[i]; s += v; s2 += v * v; }
#pragma unroll
  for (int m = 1; m < 64; m <<= 1) { s += __shfl_xor(s, m); s2 += __shfl_xor(s2, m); }
  __shared__ float red[2][4];
  const int w = threadIdx.x >> 6;
  if ((threadIdx.x & 63) == 0) { red[0][w] = s; red[1][w] = s2; }
  __syncthreads();
  s  = red[0][0] + red[0][1] + red[0][2] + red[0][3];
  s2 = red[1][0] + red[1][1] + red[1][2] + red[1][3];
  const float invD = 1.f / (float)D;
  const float mean = s * invD;
  const float var  = s2 * invD - mean * mean;
  const float rstd = rsqrtf(var + EPSV);
  const float* asrc = addsrc ? addsrc + orow * D : nullptr;
  for (int i = threadIdx.x; i < D; i += 256) {
    float v = (p[i] - mean) * rstd * g[i] + b[i];
    if (asrc) v += asrc[i];
    if (outb) outb[orow * D + i] = f2bf(v);
    else      out[orow * D + i] = v;
  }
}

// ---------------------------------------------------------------------------
// intra bi-LSTM, MFMA. grid (32, 2=dir), block 512 (8 waves).
// ---------------------------------------------------------------------------
__global__ __launch_bounds__(512) void lstm_intra_mfma(
    const unsigned short* __restrict__ zlnb,
    const unsigned short* __restrict__ wfF, const unsigned short* __restrict__ wfB,
    const float* __restrict__ bpF, const float* __restrict__ bpB,
    unsigned short* __restrict__ zcat)
{
  const int dir = blockIdx.y;
  const unsigned short* __restrict__ wf = dir ? wfB : wfF;
  const float* __restrict__ bp = dir ? bpB : bpF;
  const int n0 = blockIdx.x * 32;
  const int tid = threadIdx.x, lane = tid & 63, w = tid >> 6;
  const int j = lane & 15, lq = lane >> 4;
  __shared__ unsigned short hs[32][392];   // [row][k: 0..127 x | 128..383 h]
  for (int i = tid; i < 32 * 256; i += 512) hs[i >> 8][128 + (i & 255)] = 0;
  float c[2][2][4];
#pragma unroll
  for (int mt = 0; mt < 2; ++mt)
#pragma unroll
    for (int gp = 0; gp < 2; ++gp)
#pragma unroll
      for (int i = 0; i < 4; ++i) c[mt][gp][i] = 0.f;
  float bias[8];
#pragma unroll
  for (int nt8 = 0; nt8 < 8; ++nt8) bias[nt8] = bp[(w * 8 + nt8) * 16 + j];

  for (int s = 0; s < 16; ++s) {
    const int tt = dir ? 15 - s : s;
    { // stage x_t into hs[., 0..127]
      int r = tid >> 4, c8 = tid & 15;
      *(bf16x8*)&hs[r][c8 * 8] =
          *(const bf16x8*)(zlnb + ((size_t)((n0 + r) * 16 + tt)) * 128 + c8 * 8);
    }
    __syncthreads();
    f32x4 acc[2][8];
#pragma unroll
    for (int mt = 0; mt < 2; ++mt)
#pragma unroll
      for (int nt8 = 0; nt8 < 8; ++nt8)
#pragma unroll
        for (int e = 0; e < 4; ++e) acc[mt][nt8][e] = bias[nt8];
#pragma unroll
    for (int ks = 0; ks < 12; ++ks) {
      bf16x8 af0 = *(const bf16x8*)&hs[j][ks * 32 + lq * 8];
      bf16x8 af1 = *(const bf16x8*)&hs[16 + j][ks * 32 + lq * 8];
#pragma unroll
      for (int nt8 = 0; nt8 < 8; ++nt8) {
        int nt = w * 8 + nt8;
        bf16x8 bfr = *(const bf16x8*)(wf + (((size_t)nt * 12 + ks) * 64 + lane) * 8);
        acc[0][nt8] = __builtin_amdgcn_mfma_f32_16x16x32_bf16(af0, bfr, acc[0][nt8], 0, 0, 0);
        acc[1][nt8] = __builtin_amdgcn_mfma_f32_16x16x32_bf16(af1, bfr, acc[1][nt8], 0, 0, 0);
      }
    }
    __syncthreads();
#pragma unroll
    for (int mt = 0; mt < 2; ++mt)
#pragma unroll
      for (int gp = 0; gp < 2; ++gp) {
        int u = (w * 2 + gp) * 16 + j;
#pragma unroll
        for (int i = 0; i < 4; ++i) {
          int r = mt * 16 + lq * 4 + i;
          float ig = sigm(acc[mt][gp * 4 + 0][i]);
          float fg = sigm(acc[mt][gp * 4 + 1][i]);
          float gg = tanhfast(acc[mt][gp * 4 + 2][i]);
          float og = sigm(acc[mt][gp * 4 + 3][i]);
          float cn = fg * c[mt][gp][i] + ig * gg;
          c[mt][gp][i] = cn;
          float hv = og * tanhfast(cn);
          unsigned short hb = f2bf(hv);
          hs[r][128 + u] = hb;
          zcat[((size_t)((n0 + r) * 16 + tt)) * 512 + dir * 256 + u] = hb;
        }
      }
    __syncthreads();
  }
}

// ---------------------------------------------------------------------------
// inter LSTM chunk, MFMA v7. grid (8), block 1024 (16 waves). WG owns 16 rows.
// Wave w owns unit group w (nt = 4w..4w+3 = complete i/f/g/o quadruple for 16
// units) -> activation fully in-register. Ping-pong h in LDS: ONE barrier per
// step. bf16 xw (bias folded) prefetched one step ahead.
// ---------------------------------------------------------------------------
__global__ __launch_bounds__(1024, 1) void lstm_inter_mfma(
    const unsigned short* __restrict__ xwb, const unsigned short* __restrict__ wfI,
    float* __restrict__ hstate, float* __restrict__ cstate,
    unsigned short* __restrict__ ys, int t0)
{
  const int rr0 = blockIdx.x * 16;
  const int tid = threadIdx.x, lane = tid & 63, w = tid >> 6;   // w = unit group
  const int j = lane & 15, lq = lane >> 4;
  __shared__ unsigned short hs[2][16][264];
  for (int i = tid; i < 16 * 256; i += 1024)
    hs[0][i >> 8][i & 255] = f2bf(hstate[((size_t)(rr0 + (i >> 8))) * 256 + (i & 255)]);
  const int u = w * 16 + j;
  float c[4];
#pragma unroll
  for (int i = 0; i < 4; ++i)
    c[i] = cstate[((size_t)(rr0 + lq * 4 + i)) * 256 + u];
  // per-thread xw gather offsets (indices < 8.4M, int math fine)
  int g4[4];
#pragma unroll
  for (int q = 0; q < 4; ++q) g4[q] = gate_of(w * 4 + q, j);
  int xbase[4];
#pragma unroll
  for (int i = 0; i < 4; ++i) xbase[i] = (rr0 + lq * 4 + i) * 65536;
  // prefetch xw for step 0
  float xp[4][4];
#pragma unroll
  for (int q = 0; q < 4; ++q)
#pragma unroll
    for (int i = 0; i < 4; ++i)
      xp[q][i] = bf2f(xwb[xbase[i] + g4[q]]);
  const unsigned short* wptr = wfI + (size_t)w * 16384;  // nt=4w base: 4*8*64*8
  __syncthreads();

  for (int s = 0; s < 64; ++s) {
    const int cur = s & 1, nxt = cur ^ 1;
    f32x4 acc[4];
#pragma unroll
    for (int q = 0; q < 4; ++q)
#pragma unroll
      for (int i = 0; i < 4; ++i) acc[q][i] = xp[q][i];
    // issue next step's xw gather early — hides under the MFMA block
    const int sp1024 = ((s < 63) ? s + 1 : 63) * 1024;
    float xn[4][4];
#pragma unroll
    for (int q = 0; q < 4; ++q)
#pragma unroll
      for (int i = 0; i < 4; ++i)
        xn[q][i] = bf2f(xwb[xbase[i] + sp1024 + g4[q]]);
#pragma unroll
    for (int ks = 0; ks < 8; ++ks) {
      bf16x8 af = *(const bf16x8*)&hs[cur][j][ks * 32 + lq * 8];
#pragma unroll
      for (int q = 0; q < 4; ++q) {
        bf16x8 bw = *(const bf16x8*)(wptr + ((q * 8 + ks) * 64 + lane) * 8);
        acc[q] = __builtin_amdgcn_mfma_f32_16x16x32_bf16(af, bw, acc[q], 0, 0, 0);
      }
    }
    // activation: this thread owns unit u for rows lq*4+i (full i/f/g/o)
#pragma unroll
    for (int i = 0; i < 4; ++i) {
      int r = lq * 4 + i;
      float ig = sigm(acc[0][i]);
      float fg = sigm(acc[1][i]);
      float gg = tanhfast(acc[2][i]);
      float og = sigm(acc[3][i]);
      float cn = fg * c[i] + ig * gg;
      c[i] = cn;
      float hv = og * tanhfast(cn);
      unsigned short hb = f2bf(hv);
      hs[nxt][r][u] = hb;
      ys[((size_t)(rr0 + r) * 512 + t0 + s) * 256 + u] = hb;
    }
    __syncthreads();
#pragma unroll
    for (int q = 0; q < 4; ++q)
#pragma unroll
      for (int i = 0; i < 4; ++i) xp[q][i] = xn[q][i];
  }
  // after s=63, final h lives in hs[0]
#pragma unroll
  for (int i = 0; i < 4; ++i) {
    int r = lq * 4 + i;
    hstate[((size_t)(rr0 + r)) * 256 + u] = bf2f(hs[0][r][u]);
    cstate[((size_t)(rr0 + r)) * 256 + u] = c[i];
  }
}

// ---------------------------------------------------------------------------
// permute / epilogue kernels
// ---------------------------------------------------------------------------
__global__ __launch_bounds__(256) void perm_dec_add(
    const float* __restrict__ Cd, const float* __restrict__ x, float* __restrict__ x1)
{
  int idx = blockIdx.x * 256 + threadIdx.x; // 8,388,608
  int n = idx >> 13, f = (idx >> 7) & 63, o = idx & 127;
  x1[idx] = Cd[(size_t)(n * 16 + (f >> 2)) * 512 + (o << 2) + (f & 3)] + x[idx];
}

__global__ __launch_bounds__(256) void perm_wil_add(
    const float* __restrict__ C3, const float* __restrict__ x1,
    float* __restrict__ dout, unsigned short* __restrict__ doutb)
{
  int idx = blockIdx.x * 256 + threadIdx.x; // 8,388,608
  int rid = idx >> 7, c = idx & 127;
  int bb = rid >> 15, t = (rid >> 6) & 511, qf = rid & 63;
  float v = C3[(size_t)(((bb << 6) | qf) * 512 + t) * 128 + c] + x1[idx];
  dout[idx] = v;
  doutb[idx] = f2bf(v);
}

__global__ __launch_bounds__(256) void scat_qk(
    const unsigned short* __restrict__ C6, const float* __restrict__ bq, const float* __restrict__ bk,
    const float* __restrict__ aq, const float* __restrict__ ak,
    float* __restrict__ Qm, float* __restrict__ Km)
{
  int idx = blockIdx.x * 256 + threadIdx.x; // 4,194,304
  int row = idx >> 6, he = idx & 63;
  int bb = row >> 15, t = (row >> 6) & 511, q = row & 63;
  bool isQ = he < 32;
  int e32 = he & 31;
  float v = bf2f(C6[(size_t)row * 192 + he]) + (isQ ? bq[e32] : bk[e32]);
  float a = isQ ? aq[0] : ak[0];
  v = v >= 0.f ? v : a * v;
  float* dst = isQ ? Qm : Km;
  dst[((size_t)(bb * 4 + (e32 >> 3)) * 512 + t) * 512 + q * 8 + (e32 & 7)] = v;
}

__global__ __launch_bounds__(256) void scat_v(
    const unsigned short* __restrict__ C6, const float* __restrict__ bv,
    const float* __restrict__ av, float* __restrict__ Vm)
{
  int idx = blockIdx.x * 256 + threadIdx.x; // 8,388,608
  int row = idx >> 7, o = idx & 127;
  int bb = row >> 15, t = (row >> 6) & 511, q = row & 63;
  float v = bf2f(C6[(size_t)row * 192 + 64 + o]) + bv[o];
  v = v >= 0.f ? v : av[0] * v;
  Vm[((size_t)(bb * 4 + (o >> 5)) * 512 + t) * 2048 + q * 32 + (o & 31)] = v;
}

__global__ __launch_bounds__(256) void gather_y(
    const float* __restrict__ Vo, unsigned short* __restrict__ yg)
{
  int idx = blockIdx.x * 256 + threadIdx.x; // 8,388,608
  int rid = idx >> 7, c = idx & 127;
  int bb = rid >> 15, t = (rid >> 6) & 511, q = rid & 63;
  yg[idx] = f2bf(Vo[((size_t)(bb * 4 + (c >> 5)) * 512 + t) * 2048 + q * 32 + (c & 31)]);
}

// ---------------------------------------------------------------------------
// banded attention (fp32)
// ---------------------------------------------------------------------------
__global__ __launch_bounds__(256) void attn_scores(
    const float* __restrict__ Qm, const float* __restrict__ Km,
    const float* __restrict__ Kbuf, float* __restrict__ attnw)
{
  __shared__ float Qs[16][512];
  __shared__ float sc[16][104];
  const int tb = blockIdx.x, bh = blockIdx.y;
  const int t0 = tb * 16;
  for (int i = threadIdx.x; i < 8192; i += 256) {
    int rr = i >> 9, d = i & 511;
    Qs[rr][d] = Qm[((size_t)(bh * 512) + t0 + rr) * 512 + d];
  }
  __syncthreads();
  const int q = threadIdx.x >> 4, li = threadIdx.x & 15;
  const float isc = 0.044194173824159216f; // 1/sqrt(512)
  for (int chunk = 0; chunk < 8; ++chunk) {
    int off = chunk * 16 + li;
    int sl = off - q;
    if (off <= 114 && sl >= 0 && sl < 100) {
      int sp = t0 + off;
      const float* Kr = (sp < 99) ? (Kbuf + ((size_t)bh * 99 + sp) * 512)
                                  : (Km + ((size_t)bh * 512 + (sp - 99)) * 512);
      const float4* K4 = (const float4*)Kr;
      const float4* Q4 = (const float4*)&Qs[q][0];
      float dot = 0.f;
      for (int d4 = 0; d4 < 128; ++d4) {
        float4 kv = K4[d4], qv = Q4[d4];
        dot += kv.x * qv.x + kv.y * qv.y + kv.z * qv.z + kv.w * qv.w;
      }
      sc[q][sl] = dot * isc;
    }
  }
  __syncthreads();
  float mx = -1e30f;
  for (int s = li; s < 100; s += 16) mx = fmaxf(mx, sc[q][s]);
#pragma unroll
  for (int m = 1; m < 16; m <<= 1) mx = fmaxf(mx, __shfl_xor(mx, m, 16));
  float sum = 0.f;
  for (int s = li; s < 100; s += 16) sum += __expf(sc[q][s] - mx);
#pragma unroll
  for (int m = 1; m < 16; m <<= 1) sum += __shfl_xor(sum, m, 16);
  const float rinv = 1.f / sum;
  for (int s = li; s < 100; s += 16)
    attnw[((size_t)(bh * 512) + t0 + q) * 100 + s] = __expf(sc[q][s] - mx) * rinv;
}

__global__ __launch_bounds__(256) void attn_pv(
    const float* __restrict__ attnw, const float* __restrict__ Vm,
    const float* __restrict__ Vbuf, float* __restrict__ Vo)
{
  __shared__ float atn[8][100];
  const int qb = blockIdx.x, bh = blockIdx.y;
  const int t0 = qb * 8;
  for (int i = threadIdx.x; i < 800; i += 256) {
    int qq = i / 100, sl = i - qq * 100;
    atn[qq][sl] = attnw[((size_t)(bh * 512) + t0 + qq) * 100 + sl];
  }
  __syncthreads();
  float4 a0[8], a1[8];
#pragma unroll
  for (int qq = 0; qq < 8; ++qq) {
    a0[qq] = make_float4(0.f, 0.f, 0.f, 0.f);
    a1[qq] = make_float4(0.f, 0.f, 0.f, 0.f);
  }
  for (int jj = 0; jj < 107; ++jj) {
    int sp = t0 + jj;
    const float* Vr = (sp < 99) ? (Vbuf + ((size_t)bh * 99 + sp) * 2048)
                                : (Vm + ((size_t)bh * 512 + (sp - 99)) * 2048);
    float4 v0 = ((const float4*)Vr)[threadIdx.x * 2];
    float4 v1 = ((const float4*)Vr)[threadIdx.x * 2 + 1];
#pragma unroll
    for (int qq = 0; qq < 8; ++qq) {
      int sl = jj - qq;
      if (sl >= 0 && sl < 100) {
        float wgt = atn[qq][sl];
        a0[qq].x += wgt * v0.x; a0[qq].y += wgt * v0.y; a0[qq].z += wgt * v0.z; a0[qq].w += wgt * v0.w;
        a1[qq].x += wgt * v1.x; a1[qq].y += wgt * v1.y; a1[qq].z += wgt * v1.z; a1[qq].w += wgt * v1.w;
      }
    }
  }
#pragma unroll
  for (int qq = 0; qq < 8; ++qq) {
    float4* dst = (float4*)(Vo + ((size_t)(bh * 512) + t0 + qq) * 2048);
    dst[threadIdx.x * 2] = a0[qq];
    dst[threadIdx.x * 2 + 1] = a1[qq];
  }
}

// ---------------------------------------------------------------------------
extern "C" void kernel_launch(void* const* d_in, const int* in_sizes, int n_in,
                              void* d_out, int out_size, void* d_ws, size_t ws_size,
                              hipStream_t stream) {
  (void)in_sizes; (void)n_in; (void)out_size; (void)ws_size;
  const float* x      = (const float*)d_in[0];
  const float* Wc     = (const float*)d_in[1];
  const float* bconv  = (const float*)d_in[2];
  const float* a_act  = (const float*)d_in[3];
  const float* gnorm  = (const float*)d_in[4];
  const float* bnorm  = (const float*)d_in[5];
  const float* Wih_f  = (const float*)d_in[6];
  const float* Whh_f  = (const float*)d_in[7];
  const float* bih_f  = (const float*)d_in[8];
  const float* bhh_f  = (const float*)d_in[9];
  const float* Wih_b  = (const float*)d_in[10];
  const float* Whh_b  = (const float*)d_in[11];
  const float* bih_b  = (const float*)d_in[12];
  const float* bhh_b  = (const float*)d_in[13];
  const float* Wih_i  = (const float*)d_in[14];
  const float* Whh_i  = (const float*)d_in[15];
  const float* bih_i  = (const float*)d_in[16];
  const float* bhh_i  = (const float*)d_in[17];
  const float* Wdec   = (const float*)d_in[18];
  const float* bdec   = (const float*)d_in[19];
  const float* g_in   = (const float*)d_in[20];
  const float* b_in   = (const float*)d_in[21];
  const float* Wil    = (const float*)d_in[22];
  const float* bil    = (const float*)d_in[23];
  const float* Wq     = (const float*)d_in[24];
  const float* bq     = (const float*)d_in[25];
  const float* aq     = (const float*)d_in[26];
  const float* gq     = (const float*)d_in[27];
  const float* bgq    = (const float*)d_in[28];
  const float* Wk     = (const float*)d_in[29];
  const float* bk     = (const float*)d_in[30];
  const float* ak     = (const float*)d_in[31];
  const float* gk     = (const float*)d_in[32];
  const float* bgk    = (const float*)d_in[33];
  const float* Wv     = (const float*)d_in[34];
  const float* bv     = (const float*)d_in[35];
  const float* av     = (const float*)d_in[36];
  const float* gv     = (const float*)d_in[37];
  const float* bgv    = (const float*)d_in[38];
  const float* Wp     = (const float*)d_in[39];
  const float* bp     = (const float*)d_in[40];
  const float* ap     = (const float*)d_in[41];
  const float* gp     = (const float*)d_in[42];
  const float* bgp    = (const float*)d_in[43];
  const float* h0     = (const float*)d_in[44];
  const float* c0     = (const float*)d_in[45];
  const float* Kbuf   = (const float*)d_in[46];
  const float* Vbuf   = (const float*)d_in[47];
  float* dout = (float*)d_out;
  float* ws = (float*)d_ws;

  // region aliases (lifetime-disjoint)
  float*          zln    = ws + O_PA;                          // 2.1M fl
  float*          Cd     = ws + O_PA;                          // 8.4M fl
  unsigned short* xwb    = (unsigned short*)(ws + O_PA);       // 8.4M u16 (chunk)
  float*          C3     = ws + O_PA;                          // 8.4M fl
  unsigned short* C6     = (unsigned short*)(ws + O_PA);       // 12.6M u16
  float*          Vo     = ws + O_PA;                          // 8.4M fl
  unsigned short* x_bf   = (unsigned short*)(ws + O_PB);       // 8.4M u16
  float*          x1     = ws + O_PB;                          // 8.4M fl
  float*          Vm     = ws + O_PB;                          // 8.4M fl
  float*          y2     = ws + O_PB;                          // 8.4M fl
  unsigned short* zlnb   = (unsigned short*)(ws + O_PC);            // 2.1M u16
  unsigned short* zcat   = (unsigned short*)(ws + O_PC + 2097152);  // 8.4M u16
  unsigned short* z2b    = (unsigned short*)(ws + O_PC);            // 8.4M u16
  unsigned short* ysb    = (unsigned short*)(ws + O_PC + 4194304);  // 16.8M u16
  unsigned short* doutb  = (unsigned short*)(ws + O_PC + 8388608);  // 8.4M u16
  float*          Qm     = ws + O_PC;                          // 2.1M fl
  float*          Km     = ws + O_PC + 2097152;                // 2.1M fl
  unsigned short* ygb    = (unsigned short*)(ws + O_PC + 4194304);  // 8.4M u16
  float*          attnw  = ws + O_ATTN;

  // weight pointers
  unsigned short* WcT  = (unsigned short*)(ws + O_WCBT);
  unsigned short* WdT  = (unsigned short*)(ws + O_WDBT);
  unsigned short* WihI = (unsigned short*)(ws + O_WIHI);
  unsigned short* WilB = (unsigned short*)(ws + O_WILB);
  unsigned short* Wqkv = (unsigned short*)(ws + O_WQKV);
  unsigned short* WpB  = (unsigned short*)(ws + O_WPB);
  unsigned short* WfF  = (unsigned short*)(ws + O_WFIF);
  unsigned short* WfB  = (unsigned short*)(ws + O_WFIB);
  unsigned short* WfI  = (unsigned short*)(ws + O_WFII);

  // state init
  hipMemcpyAsync(ws + O_HI, h0, 32768 * 4, hipMemcpyDeviceToDevice, stream);
  hipMemcpyAsync(ws + O_CI, c0, 32768 * 4, hipMemcpyDeviceToDevice, stream);

  prep_weights<<<6190, 256, 0, stream>>>(Wc, Wdec, bdec, Wih_i, Wil, Wq, Wk, Wv, Wp,
      Wih_f, Whh_f, Wih_b, Whh_b, Whh_i,
      bih_f, bhh_f, bih_b, bhh_b, bih_i, bhh_i, ws);

  // ---- intra: conv (as GEMM) + prelu + LN (-> bf16) ----
  cast_f2b<<<8192, 256, 0, stream>>>(x, x_bf, 2097152);
  gemm_mfma<<<dim3(128, 1), 256, 0, stream>>>(x_bf, WcT, zln, 16384, 128, 512,
      bconv, a_act, 0, 0, 0, 0);
  ln_rows<<<16384, 256, 0, stream>>>(zln, nullptr, zlnb, 128, gnorm, bnorm, nullptr, 0);

  // ---- intra bi-LSTM (MFMA, 1 dispatch) ----
  lstm_intra_mfma<<<dim3(32, 2), 512, 0, stream>>>(zlnb, WfF, WfB,
      ws + O_BPF, ws + O_BPB, zcat);

  // ---- deconv (as GEMM) + residual ----
  gemm_mfma<<<dim3(128, 4), 256, 0, stream>>>(zcat, WdT, Cd, 16384, 512, 512,
      ws + O_BDE, nullptr, 0, 0, 0, 0);
  perm_dec_add<<<32768, 256, 0, stream>>>(Cd, x, x1);

  // ---- inter: LN (permuted, bf16) then chunked bf16-xw GEMM + MFMA LSTM ----
  ln_rows<<<65536, 256, 0, stream>>>(x1, nullptr, z2b, 128, g_in, b_in, nullptr, 1);
  for (int c = 0; c < 8; ++c) {
    gemm_mfma<<<dim3(64, 8), 256, 0, stream>>>(z2b, WihI, xwb, 8192, 1024, 128,
        ws + O_BSI, nullptr, 1, 64, 512, c * 64);
    lstm_inter_mfma<<<8, 1024, 0, stream>>>(xwb, WfI, ws + O_HI, ws + O_CI, ysb, c * 64);
  }
  gemm_mfma<<<dim3(512, 1), 256, 0, stream>>>(ysb, WilB, C3, 65536, 128, 256,
      bil, nullptr, 0, 0, 0, 0);
  perm_wil_add<<<32768, 256, 0, stream>>>(C3, x1, dout, doutb);

  // ---- attention projections (QKV fused, N=192, bf16 out) ----
  gemm_mfma<<<dim3(512, 2), 256, 0, stream>>>(doutb, Wqkv, C6, 65536, 192, 128,
      nullptr, nullptr, 1, 0, 0, 0);
  scat_qk<<<16384, 256, 0, stream>>>(C6, bq, bk, aq, ak, Qm, Km);
  scat_v<<<32768, 256, 0, stream>>>(C6, bv, av, Vm);
  ln_rows<<<4096, 256, 0, stream>>>(Qm, Qm, nullptr, 512, gq, bgq, nullptr, 0);
  ln_rows<<<4096, 256, 0, stream>>>(Km, Km, nullptr, 512, gk, bgk, nullptr, 0);
  ln_rows<<<4096, 256, 0, stream>>>(Vm, Vm, nullptr, 2048, gv, bgv, nullptr, 0);

  // ---- banded causal attention ----
  attn_scores<<<dim3(32, 8), 256, 0, stream>>>(Qm, Km, Kbuf, attnw);
  attn_pv<<<dim3(64, 8), 256, 0, stream>>>(attnw, Vm, Vbuf, Vo);

  // ---- output projection + prelu + LN + residual ----
  gather_y<<<32768, 256, 0, stream>>>(Vo, ygb);
  gemm_mfma<<<dim3(512, 1), 256, 0, stream>>>(ygb, WpB, y2, 65536, 128, 128,
      bp, ap, 0, 0, 0, 0);
  ln_rows<<<1024, 256, 0, stream>>>(y2, dout, nullptr, 8192, gp, bgp, dout, 0);
}

// Round 13
// 3477.009 us; speedup vs baseline: 1.5320x; 1.5320x over previous
//
#include <hip/hip_runtime.h>
#include <cstddef>
#include <cstdint>

// ---------------------------------------------------------------------------
// GridNetBlock forward. B=2,T=512,QF=64,C=128,H=256,KD=4,NH=4,E=8,VD=32,L=100.
// Round 13: inter-LSTM v8 — weights fully CU-resident: 384KB in VGPRs
// (192/lane across 8 waves, compile-time-indexed) + 128KB in LDS + h
// ping-pong. Zero per-step weight traffic; 1 barrier/step. Rest = R11.
// Workspace: 30,629,376 floats = 122.5 MiB.
// ---------------------------------------------------------------------------

#define EPSV 1e-5f

typedef __attribute__((ext_vector_type(8))) short bf16x8;
typedef __attribute__((ext_vector_type(4))) float f32x4;

// ---- workspace offsets (in float units) ----
#define O_WCBT  0           // 65536 u16: conv W^T rows o, cols k*128+c
#define O_WDBT  32768       // 262144 u16: deconv W^T rows o*4+k, cols c
#define O_WIHI  163840      // 131072 u16: Wih_i [1024][128]
#define O_WILB  229376      // 32768 u16: W_il [128][256]
#define O_WQKV  245760      // 24576 u16: rows 0-31 Wq, 32-63 Wk, 64-191 Wv
#define O_WPB   258048      // 16384 u16: Wp [128][128]
#define O_WFIF  266240      // 393216 u16: intra fwd frag [nt][ks12][lane][8]
#define O_WFIB  462848      // 393216 u16: intra bwd frag
#define O_WFII  659456      // 262144 u16: inter Whh frag [nt][ks8][lane][8]
#define O_BPF   790528      // 1024 fl: permuted bias intra fwd
#define O_BPB   791552      // 1024 fl: permuted bias intra bwd
#define O_BDE   792576      // 512 fl: deconv bias expanded
#define O_BSI   793088      // 1024 fl: bih_i+bhh_i (standard order, for GEMM)
#define O_HI    794112      // 32768 fl inter h state
#define O_CI    826880      // 32768 fl inter c state
#define O_ATTN  859648      // 409600 fl
#define O_PA    1269248     // 8,388,608 fl region A
#define O_PB    9657856     // 8,388,608 fl region B
#define O_PC    18046464    // 12,582,912 fl region C
// end 30,629,376 fl

static __device__ __forceinline__ float sigm(float x) { return 1.f / (1.f + __expf(-x)); }
static __device__ __forceinline__ float tanhfast(float x) { return 1.f - 2.f / (__expf(2.f * x) + 1.f); }
static __device__ __forceinline__ unsigned short f2bf(float f) {
  union { float f; uint32_t u; } v; v.f = f;
  uint32_t r = v.u + 0x7fffu + ((v.u >> 16) & 1u);
  return (unsigned short)(r >> 16);
}
static __device__ __forceinline__ float bf2f(unsigned short u) {
  union { uint32_t u; float f; } v; v.u = ((uint32_t)u) << 16;
  return v.f;
}
// permuted gate index: p = nt*16+j -> original gate (nt&3)*256 + (nt>>2)*16 + j
static __device__ __forceinline__ int gate_of(int nt, int j) {
  return (nt & 3) * 256 + ((nt >> 2) << 4) + j;
}

// ---------------------------------------------------------------------------
// weight prep (fp32 -> bf16 layouts + fragment swizzles + bias sums)
// ---------------------------------------------------------------------------
__global__ __launch_bounds__(256) void prep_weights(
    const float* __restrict__ Wc, const float* __restrict__ Wdec,
    const float* __restrict__ bdec,
    const float* __restrict__ Wih_i, const float* __restrict__ Wil,
    const float* __restrict__ Wq, const float* __restrict__ Wk,
    const float* __restrict__ Wv, const float* __restrict__ Wp,
    const float* __restrict__ Wih_f, const float* __restrict__ Whh_f,
    const float* __restrict__ Wih_b, const float* __restrict__ Whh_b,
    const float* __restrict__ Whh_i,
    const float* __restrict__ bih_f, const float* __restrict__ bhh_f,
    const float* __restrict__ bih_b, const float* __restrict__ bhh_b,
    const float* __restrict__ bih_i, const float* __restrict__ bhh_i,
    float* __restrict__ ws)
{
  int idx = blockIdx.x * 256 + threadIdx.x;
  if (idx < 65536) { // WcT_bt[o][k*128+c] = Wc[o][c][k]
    int o = idx >> 9, kc = idx & 511, k = kc >> 7, c = kc & 127;
    ((unsigned short*)(ws + O_WCBT))[idx] = f2bf(Wc[o * 512 + c * 4 + k]);
    return;
  }
  idx -= 65536;
  if (idx < 262144) { // Wd_bt[ok][c] = Wdec[c*512+ok]
    int ok = idx >> 9, c = idx & 511;
    ((unsigned short*)(ws + O_WDBT))[idx] = f2bf(Wdec[c * 512 + ok]);
    return;
  }
  idx -= 262144;
  if (idx < 131072) { ((unsigned short*)(ws + O_WIHI))[idx] = f2bf(Wih_i[idx]); return; }
  idx -= 131072;
  if (idx < 32768) { ((unsigned short*)(ws + O_WILB))[idx] = f2bf(Wil[idx]); return; }
  idx -= 32768;
  if (idx < 24576) { // Wqkv rows: 0-31 Wq, 32-63 Wk, 64-191 Wv
    int row = idx >> 7, c = idx & 127;
    float v = (row < 32) ? Wq[row * 128 + c]
            : (row < 64) ? Wk[(row - 32) * 128 + c]
                         : Wv[(row - 64) * 128 + c];
    ((unsigned short*)(ws + O_WQKV))[idx] = f2bf(v);
    return;
  }
  idx -= 24576;
  if (idx < 16384) { ((unsigned short*)(ws + O_WPB))[idx] = f2bf(Wp[idx]); return; }
  idx -= 16384;
  if (idx < 393216) { // intra fwd frag: [((nt*12+ks)*64+l)*8+e], K=384=[x|h]
    int e = idx & 7, l = (idx >> 3) & 63, t = idx >> 9;
    int ks = t % 12, nt = t / 12;
    int gate = gate_of(nt, l & 15);
    int k = ks * 32 + (l >> 4) * 8 + e;
    float v = (k < 128) ? Wih_f[gate * 128 + k] : Whh_f[gate * 256 + (k - 128)];
    ((unsigned short*)(ws + O_WFIF))[idx] = f2bf(v);
    return;
  }
  idx -= 393216;
  if (idx < 393216) { // intra bwd frag
    int e = idx & 7, l = (idx >> 3) & 63, t = idx >> 9;
    int ks = t % 12, nt = t / 12;
    int gate = gate_of(nt, l & 15);
    int k = ks * 32 + (l >> 4) * 8 + e;
    float v = (k < 128) ? Wih_b[gate * 128 + k] : Whh_b[gate * 256 + (k - 128)];
    ((unsigned short*)(ws + O_WFIB))[idx] = f2bf(v);
    return;
  }
  idx -= 393216;
  if (idx < 262144) { // inter Whh frag: [((nt*8+ks)*64+l)*8+e], K=256
    int e = idx & 7, l = (idx >> 3) & 63, t = idx >> 9;
    int ks = t & 7, nt = t >> 3;
    int gate = gate_of(nt, l & 15);
    int k = ks * 32 + (l >> 4) * 8 + e;
    ((unsigned short*)(ws + O_WFII))[idx] = f2bf(Whh_i[gate * 256 + k]);
    return;
  }
  idx -= 262144;
  if (idx < 512) { ws[O_BDE + idx] = bdec[idx >> 2]; return; }
  idx -= 512;
  if (idx < 1024) { // permuted intra fwd bias
    int gate = gate_of(idx >> 4, idx & 15);
    ws[O_BPF + idx] = bih_f[gate] + bhh_f[gate];
    return;
  }
  idx -= 1024;
  if (idx < 1024) {
    int gate = gate_of(idx >> 4, idx & 15);
    ws[O_BPB + idx] = bih_b[gate] + bhh_b[gate];
    return;
  }
  idx -= 1024;
  if (idx < 1024) { ws[O_BSI + idx] = bih_i[idx] + bhh_i[idx]; return; }
}

// fp32 -> bf16 cast, 4 elems/thread
__global__ __launch_bounds__(256) void cast_f2b(
    const float* __restrict__ in, unsigned short* __restrict__ out, int n4)
{
  int i = blockIdx.x * 256 + threadIdx.x;
  if (i >= n4) return;
  float4 v = ((const float4*)in)[i];
  ushort4 o;
  o.x = f2bf(v.x); o.y = f2bf(v.y); o.z = f2bf(v.z); o.w = f2bf(v.w);
  ((ushort4*)out)[i] = o;
}

// ---------------------------------------------------------------------------
// bf16 MFMA GEMM: C[M][N] = A[M][K] * Bt[N][K]^T (+bias[N]) (+prelu)
// Optional A-row remap for time-chunked GEMMs; optional bf16 output.
// ---------------------------------------------------------------------------
__global__ __launch_bounds__(256) void gemm_mfma(
    const unsigned short* __restrict__ A, const unsigned short* __restrict__ Bt,
    void* __restrict__ Cout, int M, int N, int K,
    const float* __restrict__ bias, const float* __restrict__ pa, int c_bf16,
    int a_chunk, int a_stride, int a_t0)
{
  __shared__ unsigned short As[128 * 72];
  __shared__ unsigned short Bs[128 * 72];
  const int bm = blockIdx.x * 128, bn = blockIdx.y * 128;
  const int tid = threadIdx.x, lane = tid & 63, wave = tid >> 6;
  const int wm = (wave >> 1) * 64, wn = (wave & 1) * 64;
  f32x4 acc[4][4];
#pragma unroll
  for (int i = 0; i < 4; ++i)
#pragma unroll
    for (int j = 0; j < 4; ++j)
#pragma unroll
      for (int e = 0; e < 4; ++e) acc[i][j][e] = 0.f;

  for (int k0 = 0; k0 < K; k0 += 64) {
#pragma unroll
    for (int it = 0; it < 4; ++it) {
      int ch = tid + it * 256;          // 0..1023
      int r = ch >> 3, kc = ch & 7;
      int arow = bm + r;
      if (a_chunk) arow = (arow / a_chunk) * a_stride + a_t0 + (arow % a_chunk);
      *(bf16x8*)&As[r * 72 + kc * 8] =
          *(const bf16x8*)(A + (size_t)arow * K + k0 + kc * 8);
      int nrow = bn + r; if (nrow > N - 1) nrow = N - 1;
      *(bf16x8*)&Bs[r * 72 + kc * 8] =
          *(const bf16x8*)(Bt + (size_t)nrow * K + k0 + kc * 8);
    }
    __syncthreads();
#pragma unroll
    for (int kk = 0; kk < 64; kk += 32) {
      const int kb = kk + (lane >> 4) * 8;
      bf16x8 af[4], bfr[4];
#pragma unroll
      for (int mb = 0; mb < 4; ++mb)
        af[mb] = *(const bf16x8*)&As[(wm + mb * 16 + (lane & 15)) * 72 + kb];
#pragma unroll
      for (int nb = 0; nb < 4; ++nb)
        bfr[nb] = *(const bf16x8*)&Bs[(wn + nb * 16 + (lane & 15)) * 72 + kb];
#pragma unroll
      for (int mb = 0; mb < 4; ++mb)
#pragma unroll
        for (int nb = 0; nb < 4; ++nb)
          acc[mb][nb] = __builtin_amdgcn_mfma_f32_16x16x32_bf16(
              af[mb], bfr[nb], acc[mb][nb], 0, 0, 0);
    }
    __syncthreads();
  }
  const float aval = pa ? pa[0] : 0.f;
#pragma unroll
  for (int mb = 0; mb < 4; ++mb) {
#pragma unroll
    for (int nb = 0; nb < 4; ++nb) {
      int col = bn + wn + nb * 16 + (lane & 15);
      if (col >= N) continue;
      float bv = bias ? bias[col] : 0.f;
#pragma unroll
      for (int i = 0; i < 4; ++i) {
        int row = bm + wm + mb * 16 + (lane >> 4) * 4 + i;
        float v = acc[mb][nb][i] + bv;
        if (pa) v = v >= 0.f ? v : aval * v;
        if (c_bf16) ((unsigned short*)Cout)[(size_t)row * N + col] = f2bf(v);
        else        ((float*)Cout)[(size_t)row * N + col] = v;
      }
    }
  }
}

// ---------------------------------------------------------------------------
// LayerNorm over last dim D; optional output row-perm; optional residual add;
// optional bf16 output.
// ---------------------------------------------------------------------------
__global__ __launch_bounds__(256) void ln_rows(
    const float* in, float* out, unsigned short* outb, int D,
    const float* __restrict__ g, const float* __restrict__ b,
    const float* addsrc, int permmode)
{
  const int row = blockIdx.x;
  size_t orow = row;
  if (permmode == 1) {
    int bb = row >> 15, t = (row >> 6) & 511, qf = row & 63;
    orow = (size_t)((bb << 6) | qf) * 512 + t;
  }
  const float* p = in + (size_t)row * D;
  float s = 0.f, s2 = 0.f;
  for (int i = threadIdx.x; i < D; i += 256) { float v = p[i]; s += v; s2 += v * v; }
#pragma unroll
  for (int m = 1; m < 64; m <<= 1) { s += __shfl_xor(s, m); s2 += __shfl_xor(s2, m); }
  __shared__ float red[2][4];
  const int w = threadIdx.x >> 6;
  if ((threadIdx.x & 63) == 0) { red[0][w] = s; red[1][w] = s2; }
  __syncthreads();
  s  = red[0][0] + red[0][1] + red[0][2] + red[0][3];
  s2 = red[1][0] + red[1][1] + red[1][2] + red[1][3];
  const float invD = 1.f / (float)D;
  const float mean = s * invD;
  const float var  = s2 * invD - mean * mean;
  const float rstd = rsqrtf(var + EPSV);
  const float* asrc = addsrc ? addsrc + orow * D : nullptr;
  for (int i = threadIdx.x; i < D; i += 256) {
    float v = (p[i] - mean) * rstd * g[i] + b[i];
    if (asrc) v += asrc[i];
    if (outb) outb[orow * D + i] = f2bf(v);
    else      out[orow * D + i] = v;
  }
}

// ---------------------------------------------------------------------------
// intra bi-LSTM, MFMA. grid (32, 2=dir), block 512 (8 waves).
// ---------------------------------------------------------------------------
__global__ __launch_bounds__(512) void lstm_intra_mfma(
    const unsigned short* __restrict__ zlnb,
    const unsigned short* __restrict__ wfF, const unsigned short* __restrict__ wfB,
    const float* __restrict__ bpF, const float* __restrict__ bpB,
    unsigned short* __restrict__ zcat)
{
  const int dir = blockIdx.y;
  const unsigned short* __restrict__ wf = dir ? wfB : wfF;
  const float* __restrict__ bp = dir ? bpB : bpF;
  const int n0 = blockIdx.x * 32;
  const int tid = threadIdx.x, lane = tid & 63, w = tid >> 6;
  const int j = lane & 15, lq = lane >> 4;
  __shared__ unsigned short hs[32][392];   // [row][k: 0..127 x | 128..383 h]
  for (int i = tid; i < 32 * 256; i += 512) hs[i >> 8][128 + (i & 255)] = 0;
  float c[2][2][4];
#pragma unroll
  for (int mt = 0; mt < 2; ++mt)
#pragma unroll
    for (int gp = 0; gp < 2; ++gp)
#pragma unroll
      for (int i = 0; i < 4; ++i) c[mt][gp][i] = 0.f;
  float bias[8];
#pragma unroll
  for (int nt8 = 0; nt8 < 8; ++nt8) bias[nt8] = bp[(w * 8 + nt8) * 16 + j];

  for (int s = 0; s < 16; ++s) {
    const int tt = dir ? 15 - s : s;
    { // stage x_t into hs[., 0..127]
      int r = tid >> 4, c8 = tid & 15;
      *(bf16x8*)&hs[r][c8 * 8] =
          *(const bf16x8*)(zlnb + ((size_t)((n0 + r) * 16 + tt)) * 128 + c8 * 8);
    }
    __syncthreads();
    f32x4 acc[2][8];
#pragma unroll
    for (int mt = 0; mt < 2; ++mt)
#pragma unroll
      for (int nt8 = 0; nt8 < 8; ++nt8)
#pragma unroll
        for (int e = 0; e < 4; ++e) acc[mt][nt8][e] = bias[nt8];
#pragma unroll
    for (int ks = 0; ks < 12; ++ks) {
      bf16x8 af0 = *(const bf16x8*)&hs[j][ks * 32 + lq * 8];
      bf16x8 af1 = *(const bf16x8*)&hs[16 + j][ks * 32 + lq * 8];
#pragma unroll
      for (int nt8 = 0; nt8 < 8; ++nt8) {
        int nt = w * 8 + nt8;
        bf16x8 bfr = *(const bf16x8*)(wf + (((size_t)nt * 12 + ks) * 64 + lane) * 8);
        acc[0][nt8] = __builtin_amdgcn_mfma_f32_16x16x32_bf16(af0, bfr, acc[0][nt8], 0, 0, 0);
        acc[1][nt8] = __builtin_amdgcn_mfma_f32_16x16x32_bf16(af1, bfr, acc[1][nt8], 0, 0, 0);
      }
    }
    __syncthreads();
#pragma unroll
    for (int mt = 0; mt < 2; ++mt)
#pragma unroll
      for (int gp = 0; gp < 2; ++gp) {
        int u = (w * 2 + gp) * 16 + j;
#pragma unroll
        for (int i = 0; i < 4; ++i) {
          int r = mt * 16 + lq * 4 + i;
          float ig = sigm(acc[mt][gp * 4 + 0][i]);
          float fg = sigm(acc[mt][gp * 4 + 1][i]);
          float gg = tanhfast(acc[mt][gp * 4 + 2][i]);
          float og = sigm(acc[mt][gp * 4 + 3][i]);
          float cn = fg * c[mt][gp][i] + ig * gg;
          c[mt][gp][i] = cn;
          float hv = og * tanhfast(cn);
          unsigned short hb = f2bf(hv);
          hs[r][128 + u] = hb;
          zcat[((size_t)((n0 + r) * 16 + tt)) * 512 + dir * 256 + u] = hb;
        }
      }
    __syncthreads();
  }
}

// ---------------------------------------------------------------------------
// inter LSTM chunk, MFMA v8. grid (8), block 512 (8 waves). WG owns 16 rows.
// ALL weights CU-resident: wave w's nt 0..5 in VGPRs (192/lane, compile-time
// indexed), nt 6..7 in LDS (128 KB). h ping-pong in LDS, 1 barrier/step.
// Per step: zero weight traffic; only 32 xw gathers + 16 ds_reads + 64 MFMAs.
// ---------------------------------------------------------------------------
__global__ __launch_bounds__(512, 1) void lstm_inter_mfma(
    const unsigned short* __restrict__ xwb, const unsigned short* __restrict__ wfI,
    float* __restrict__ hstate, float* __restrict__ cstate,
    unsigned short* __restrict__ ys, int t0)
{
  const int rr0 = blockIdx.x * 16;
  const int tid = threadIdx.x, lane = tid & 63, w = tid >> 6;  // 8 waves
  const int j = lane & 15, lq = lane >> 4;
  __shared__ unsigned short wlds[8 * 16 * 64 * 8];   // 128 KB: per-wave nt 6,7
  __shared__ unsigned short hs[2][16][264];          // ping-pong h

  // ---- weights -> VGPRs (nt_local 0..5; all indices compile-time) ----
  bf16x8 wv[6][8];
#pragma unroll
  for (int n = 0; n < 6; ++n)
#pragma unroll
    for (int ks = 0; ks < 8; ++ks)
      wv[n][ks] = *(const bf16x8*)(wfI + (((size_t)(w * 8 + n) * 8 + ks) * 64 + lane) * 8);
  // ---- weights -> LDS (nt_local 6,7) ----
  for (int f = 0; f < 16; ++f) {
    int n = 6 + (f >> 3), ks = f & 7;
    *(bf16x8*)&wlds[((w * 16 + f) * 64 + lane) * 8] =
        *(const bf16x8*)(wfI + (((size_t)(w * 8 + n) * 8 + ks) * 64 + lane) * 8);
  }
  // ---- h, c state ----
  for (int i = tid; i < 16 * 256; i += 512)
    hs[0][i >> 8][i & 255] = f2bf(hstate[((size_t)(rr0 + (i >> 8))) * 256 + (i & 255)]);
  float c[2][4];
#pragma unroll
  for (int qd = 0; qd < 2; ++qd) {
    int u = w * 32 + qd * 16 + j;
#pragma unroll
    for (int i = 0; i < 4; ++i)
      c[qd][i] = cstate[((size_t)(rr0 + lq * 4 + i)) * 256 + u];
  }
  // xw addressing: row base + per-quad gate base (gate offsets are
  // q*256 + (w*32 + qd*16) + j, q compile-time)
  const int xrow0 = (rr0 + lq * 4) * 65536;
  const int gb0 = w * 32 + j;        // quad 0 gate base
  __syncthreads();

  for (int s = 0; s < 64; ++s) {
    const int cur = s & 1, nxt = cur ^ 1;
    const int xs = xrow0 + s * 1024;
    // ================= quad 0 (nt_local 0..3, units w*32 + j) =============
    {
      f32x4 acc[4];
#pragma unroll
      for (int q = 0; q < 4; ++q)
#pragma unroll
        for (int i = 0; i < 4; ++i)
          acc[q][i] = bf2f(xwb[xs + i * 65536 + q * 256 + gb0]);
#pragma unroll
      for (int ks = 0; ks < 8; ++ks) {
        bf16x8 af = *(const bf16x8*)&hs[cur][j][ks * 32 + lq * 8];
#pragma unroll
        for (int q = 0; q < 4; ++q)
          acc[q] = __builtin_amdgcn_mfma_f32_16x16x32_bf16(af, wv[q][ks], acc[q], 0, 0, 0);
      }
      const int u = w * 32 + j;
#pragma unroll
      for (int i = 0; i < 4; ++i) {
        int r = lq * 4 + i;
        float ig = sigm(acc[0][i]);
        float fg = sigm(acc[1][i]);
        float gg = tanhfast(acc[2][i]);
        float og = sigm(acc[3][i]);
        float cn = fg * c[0][i] + ig * gg;
        c[0][i] = cn;
        float hv = og * tanhfast(cn);
        unsigned short hb = f2bf(hv);
        hs[nxt][r][u] = hb;
        ys[((size_t)(rr0 + r) * 512 + t0 + s) * 256 + u] = hb;
      }
    }
    // ================= quad 1 (nt_local 4..7, units w*32+16 + j) ==========
    {
      f32x4 acc[4];
#pragma unroll
      for (int q = 0; q < 4; ++q)
#pragma unroll
        for (int i = 0; i < 4; ++i)
          acc[q][i] = bf2f(xwb[xs + i * 65536 + q * 256 + gb0 + 16]);
#pragma unroll
      for (int ks = 0; ks < 8; ++ks) {
        bf16x8 af = *(const bf16x8*)&hs[cur][j][ks * 32 + lq * 8];
        acc[0] = __builtin_amdgcn_mfma_f32_16x16x32_bf16(af, wv[4][ks], acc[0], 0, 0, 0);
        acc[1] = __builtin_amdgcn_mfma_f32_16x16x32_bf16(af, wv[5][ks], acc[1], 0, 0, 0);
        bf16x8 w6 = *(const bf16x8*)&wlds[((w * 16 + ks) * 64 + lane) * 8];
        acc[2] = __builtin_amdgcn_mfma_f32_16x16x32_bf16(af, w6, acc[2], 0, 0, 0);
        bf16x8 w7 = *(const bf16x8*)&wlds[((w * 16 + 8 + ks) * 64 + lane) * 8];
        acc[3] = __builtin_amdgcn_mfma_f32_16x16x32_bf16(af, w7, acc[3], 0, 0, 0);
      }
      const int u = w * 32 + 16 + j;
#pragma unroll
      for (int i = 0; i < 4; ++i) {
        int r = lq * 4 + i;
        float ig = sigm(acc[0][i]);
        float fg = sigm(acc[1][i]);
        float gg = tanhfast(acc[2][i]);
        float og = sigm(acc[3][i]);
        float cn = fg * c[1][i] + ig * gg;
        c[1][i] = cn;
        float hv = og * tanhfast(cn);
        unsigned short hb = f2bf(hv);
        hs[nxt][r][u] = hb;
        ys[((size_t)(rr0 + r) * 512 + t0 + s) * 256 + u] = hb;
      }
    }
    __syncthreads();
  }
  // after s=63 the final h is in hs[0]
#pragma unroll
  for (int qd = 0; qd < 2; ++qd) {
    int u = w * 32 + qd * 16 + j;
#pragma unroll
    for (int i = 0; i < 4; ++i) {
      int r = lq * 4 + i;
      hstate[((size_t)(rr0 + r)) * 256 + u] = bf2f(hs[0][r][u]);
      cstate[((size_t)(rr0 + r)) * 256 + u] = c[qd][i];
    }
  }
}

// ---------------------------------------------------------------------------
// permute / epilogue kernels
// ---------------------------------------------------------------------------
__global__ __launch_bounds__(256) void perm_dec_add(
    const float* __restrict__ Cd, const float* __restrict__ x, float* __restrict__ x1)
{
  int idx = blockIdx.x * 256 + threadIdx.x; // 8,388,608
  int n = idx >> 13, f = (idx >> 7) & 63, o = idx & 127;
  x1[idx] = Cd[(size_t)(n * 16 + (f >> 2)) * 512 + (o << 2) + (f & 3)] + x[idx];
}

__global__ __launch_bounds__(256) void perm_wil_add(
    const float* __restrict__ C3, const float* __restrict__ x1,
    float* __restrict__ dout, unsigned short* __restrict__ doutb)
{
  int idx = blockIdx.x * 256 + threadIdx.x; // 8,388,608
  int rid = idx >> 7, c = idx & 127;
  int bb = rid >> 15, t = (rid >> 6) & 511, qf = rid & 63;
  float v = C3[(size_t)(((bb << 6) | qf) * 512 + t) * 128 + c] + x1[idx];
  dout[idx] = v;
  doutb[idx] = f2bf(v);
}

__global__ __launch_bounds__(256) void scat_qk(
    const unsigned short* __restrict__ C6, const float* __restrict__ bq, const float* __restrict__ bk,
    const float* __restrict__ aq, const float* __restrict__ ak,
    float* __restrict__ Qm, float* __restrict__ Km)
{
  int idx = blockIdx.x * 256 + threadIdx.x; // 4,194,304
  int row = idx >> 6, he = idx & 63;
  int bb = row >> 15, t = (row >> 6) & 511, q = row & 63;
  bool isQ = he < 32;
  int e32 = he & 31;
  float v = bf2f(C6[(size_t)row * 192 + he]) + (isQ ? bq[e32] : bk[e32]);
  float a = isQ ? aq[0] : ak[0];
  v = v >= 0.f ? v : a * v;
  float* dst = isQ ? Qm : Km;
  dst[((size_t)(bb * 4 + (e32 >> 3)) * 512 + t) * 512 + q * 8 + (e32 & 7)] = v;
}

__global__ __launch_bounds__(256) void scat_v(
    const unsigned short* __restrict__ C6, const float* __restrict__ bv,
    const float* __restrict__ av, float* __restrict__ Vm)
{
  int idx = blockIdx.x * 256 + threadIdx.x; // 8,388,608
  int row = idx >> 7, o = idx & 127;
  int bb = row >> 15, t = (row >> 6) & 511, q = row & 63;
  float v = bf2f(C6[(size_t)row * 192 + 64 + o]) + bv[o];
  v = v >= 0.f ? v : av[0] * v;
  Vm[((size_t)(bb * 4 + (o >> 5)) * 512 + t) * 2048 + q * 32 + (o & 31)] = v;
}

__global__ __launch_bounds__(256) void gather_y(
    const float* __restrict__ Vo, unsigned short* __restrict__ yg)
{
  int idx = blockIdx.x * 256 + threadIdx.x; // 8,388,608
  int rid = idx >> 7, c = idx & 127;
  int bb = rid >> 15, t = (rid >> 6) & 511, q = rid & 63;
  yg[idx] = f2bf(Vo[((size_t)(bb * 4 + (c >> 5)) * 512 + t) * 2048 + q * 32 + (c & 31)]);
}

// ---------------------------------------------------------------------------
// banded attention (fp32)
// ---------------------------------------------------------------------------
__global__ __launch_bounds__(256) void attn_scores(
    const float* __restrict__ Qm, const float* __restrict__ Km,
    const float* __restrict__ Kbuf, float* __restrict__ attnw)
{
  __shared__ float Qs[16][512];
  __shared__ float sc[16][104];
  const int tb = blockIdx.x, bh = blockIdx.y;
  const int t0 = tb * 16;
  for (int i = threadIdx.x; i < 8192; i += 256) {
    int rr = i >> 9, d = i & 511;
    Qs[rr][d] = Qm[((size_t)(bh * 512) + t0 + rr) * 512 + d];
  }
  __syncthreads();
  const int q = threadIdx.x >> 4, li = threadIdx.x & 15;
  const float isc = 0.044194173824159216f; // 1/sqrt(512)
  for (int chunk = 0; chunk < 8; ++chunk) {
    int off = chunk * 16 + li;
    int sl = off - q;
    if (off <= 114 && sl >= 0 && sl < 100) {
      int sp = t0 + off;
      const float* Kr = (sp < 99) ? (Kbuf + ((size_t)bh * 99 + sp) * 512)
                                  : (Km + ((size_t)bh * 512 + (sp - 99)) * 512);
      const float4* K4 = (const float4*)Kr;
      const float4* Q4 = (const float4*)&Qs[q][0];
      float dot = 0.f;
      for (int d4 = 0; d4 < 128; ++d4) {
        float4 kv = K4[d4], qv = Q4[d4];
        dot += kv.x * qv.x + kv.y * qv.y + kv.z * qv.z + kv.w * qv.w;
      }
      sc[q][sl] = dot * isc;
    }
  }
  __syncthreads();
  float mx = -1e30f;
  for (int s = li; s < 100; s += 16) mx = fmaxf(mx, sc[q][s]);
#pragma unroll
  for (int m = 1; m < 16; m <<= 1) mx = fmaxf(mx, __shfl_xor(mx, m, 16));
  float sum = 0.f;
  for (int s = li; s < 100; s += 16) sum += __expf(sc[q][s] - mx);
#pragma unroll
  for (int m = 1; m < 16; m <<= 1) sum += __shfl_xor(sum, m, 16);
  const float rinv = 1.f / sum;
  for (int s = li; s < 100; s += 16)
    attnw[((size_t)(bh * 512) + t0 + q) * 100 + s] = __expf(sc[q][s] - mx) * rinv;
}

__global__ __launch_bounds__(256) void attn_pv(
    const float* __restrict__ attnw, const float* __restrict__ Vm,
    const float* __restrict__ Vbuf, float* __restrict__ Vo)
{
  __shared__ float atn[8][100];
  const int qb = blockIdx.x, bh = blockIdx.y;
  const int t0 = qb * 8;
  for (int i = threadIdx.x; i < 800; i += 256) {
    int qq = i / 100, sl = i - qq * 100;
    atn[qq][sl] = attnw[((size_t)(bh * 512) + t0 + qq) * 100 + sl];
  }
  __syncthreads();
  float4 a0[8], a1[8];
#pragma unroll
  for (int qq = 0; qq < 8; ++qq) {
    a0[qq] = make_float4(0.f, 0.f, 0.f, 0.f);
    a1[qq] = make_float4(0.f, 0.f, 0.f, 0.f);
  }
  for (int jj = 0; jj < 107; ++jj) {
    int sp = t0 + jj;
    const float* Vr = (sp < 99) ? (Vbuf + ((size_t)bh * 99 + sp) * 2048)
                                : (Vm + ((size_t)bh * 512 + (sp - 99)) * 2048);
    float4 v0 = ((const float4*)Vr)[threadIdx.x * 2];
    float4 v1 = ((const float4*)Vr)[threadIdx.x * 2 + 1];
#pragma unroll
    for (int qq = 0; qq < 8; ++qq) {
      int sl = jj - qq;
      if (sl >= 0 && sl < 100) {
        float wgt = atn[qq][sl];
        a0[qq].x += wgt * v0.x; a0[qq].y += wgt * v0.y; a0[qq].z += wgt * v0.z; a0[qq].w += wgt * v0.w;
        a1[qq].x += wgt * v1.x; a1[qq].y += wgt * v1.y; a1[qq].z += wgt * v1.z; a1[qq].w += wgt * v1.w;
      }
    }
  }
#pragma unroll
  for (int qq = 0; qq < 8; ++qq) {
    float4* dst = (float4*)(Vo + ((size_t)(bh * 512) + t0 + qq) * 2048);
    dst[threadIdx.x * 2] = a0[qq];
    dst[threadIdx.x * 2 + 1] = a1[qq];
  }
}

// ---------------------------------------------------------------------------
extern "C" void kernel_launch(void* const* d_in, const int* in_sizes, int n_in,
                              void* d_out, int out_size, void* d_ws, size_t ws_size,
                              hipStream_t stream) {
  (void)in_sizes; (void)n_in; (void)out_size; (void)ws_size;
  const float* x      = (const float*)d_in[0];
  const float* Wc     = (const float*)d_in[1];
  const float* bconv  = (const float*)d_in[2];
  const float* a_act  = (const float*)d_in[3];
  const float* gnorm  = (const float*)d_in[4];
  const float* bnorm  = (const float*)d_in[5];
  const float* Wih_f  = (const float*)d_in[6];
  const float* Whh_f  = (const float*)d_in[7];
  const float* bih_f  = (const float*)d_in[8];
  const float* bhh_f  = (const float*)d_in[9];
  const float* Wih_b  = (const float*)d_in[10];
  const float* Whh_b  = (const float*)d_in[11];
  const float* bih_b  = (const float*)d_in[12];
  const float* bhh_b  = (const float*)d_in[13];
  const float* Wih_i  = (const float*)d_in[14];
  const float* Whh_i  = (const float*)d_in[15];
  const float* bih_i  = (const float*)d_in[16];
  const float* bhh_i  = (const float*)d_in[17];
  const float* Wdec   = (const float*)d_in[18];
  const float* bdec   = (const float*)d_in[19];
  const float* g_in   = (const float*)d_in[20];
  const float* b_in   = (const float*)d_in[21];
  const float* Wil    = (const float*)d_in[22];
  const float* bil    = (const float*)d_in[23];
  const float* Wq     = (const float*)d_in[24];
  const float* bq     = (const float*)d_in[25];
  const float* aq     = (const float*)d_in[26];
  const float* gq     = (const float*)d_in[27];
  const float* bgq    = (const float*)d_in[28];
  const float* Wk     = (const float*)d_in[29];
  const float* bk     = (const float*)d_in[30];
  const float* ak     = (const float*)d_in[31];
  const float* gk     = (const float*)d_in[32];
  const float* bgk    = (const float*)d_in[33];
  const float* Wv     = (const float*)d_in[34];
  const float* bv     = (const float*)d_in[35];
  const float* av     = (const float*)d_in[36];
  const float* gv     = (const float*)d_in[37];
  const float* bgv    = (const float*)d_in[38];
  const float* Wp     = (const float*)d_in[39];
  const float* bp     = (const float*)d_in[40];
  const float* ap     = (const float*)d_in[41];
  const float* gp     = (const float*)d_in[42];
  const float* bgp    = (const float*)d_in[43];
  const float* h0     = (const float*)d_in[44];
  const float* c0     = (const float*)d_in[45];
  const float* Kbuf   = (const float*)d_in[46];
  const float* Vbuf   = (const float*)d_in[47];
  float* dout = (float*)d_out;
  float* ws = (float*)d_ws;

  // region aliases (lifetime-disjoint)
  float*          zln    = ws + O_PA;                          // 2.1M fl
  float*          Cd     = ws + O_PA;                          // 8.4M fl
  unsigned short* xwb    = (unsigned short*)(ws + O_PA);       // 8.4M u16 (chunk)
  float*          C3     = ws + O_PA;                          // 8.4M fl
  unsigned short* C6     = (unsigned short*)(ws + O_PA);       // 12.6M u16
  float*          Vo     = ws + O_PA;                          // 8.4M fl
  unsigned short* x_bf   = (unsigned short*)(ws + O_PB);       // 8.4M u16
  float*          x1     = ws + O_PB;                          // 8.4M fl
  float*          Vm     = ws + O_PB;                          // 8.4M fl
  float*          y2     = ws + O_PB;                          // 8.4M fl
  unsigned short* zlnb   = (unsigned short*)(ws + O_PC);            // 2.1M u16
  unsigned short* zcat   = (unsigned short*)(ws + O_PC + 2097152);  // 8.4M u16
  unsigned short* z2b    = (unsigned short*)(ws + O_PC);            // 8.4M u16
  unsigned short* ysb    = (unsigned short*)(ws + O_PC + 4194304);  // 16.8M u16
  unsigned short* doutb  = (unsigned short*)(ws + O_PC + 8388608);  // 8.4M u16
  float*          Qm     = ws + O_PC;                          // 2.1M fl
  float*          Km     = ws + O_PC + 2097152;                // 2.1M fl
  unsigned short* ygb    = (unsigned short*)(ws + O_PC + 4194304);  // 8.4M u16
  float*          attnw  = ws + O_ATTN;

  // weight pointers
  unsigned short* WcT  = (unsigned short*)(ws + O_WCBT);
  unsigned short* WdT  = (unsigned short*)(ws + O_WDBT);
  unsigned short* WihI = (unsigned short*)(ws + O_WIHI);
  unsigned short* WilB = (unsigned short*)(ws + O_WILB);
  unsigned short* Wqkv = (unsigned short*)(ws + O_WQKV);
  unsigned short* WpB  = (unsigned short*)(ws + O_WPB);
  unsigned short* WfF  = (unsigned short*)(ws + O_WFIF);
  unsigned short* WfB  = (unsigned short*)(ws + O_WFIB);
  unsigned short* WfI  = (unsigned short*)(ws + O_WFII);

  // state init
  hipMemcpyAsync(ws + O_HI, h0, 32768 * 4, hipMemcpyDeviceToDevice, stream);
  hipMemcpyAsync(ws + O_CI, c0, 32768 * 4, hipMemcpyDeviceToDevice, stream);

  prep_weights<<<6190, 256, 0, stream>>>(Wc, Wdec, bdec, Wih_i, Wil, Wq, Wk, Wv, Wp,
      Wih_f, Whh_f, Wih_b, Whh_b, Whh_i,
      bih_f, bhh_f, bih_b, bhh_b, bih_i, bhh_i, ws);

  // ---- intra: conv (as GEMM) + prelu + LN (-> bf16) ----
  cast_f2b<<<8192, 256, 0, stream>>>(x, x_bf, 2097152);
  gemm_mfma<<<dim3(128, 1), 256, 0, stream>>>(x_bf, WcT, zln, 16384, 128, 512,
      bconv, a_act, 0, 0, 0, 0);
  ln_rows<<<16384, 256, 0, stream>>>(zln, nullptr, zlnb, 128, gnorm, bnorm, nullptr, 0);

  // ---- intra bi-LSTM (MFMA, 1 dispatch) ----
  lstm_intra_mfma<<<dim3(32, 2), 512, 0, stream>>>(zlnb, WfF, WfB,
      ws + O_BPF, ws + O_BPB, zcat);

  // ---- deconv (as GEMM) + residual ----
  gemm_mfma<<<dim3(128, 4), 256, 0, stream>>>(zcat, WdT, Cd, 16384, 512, 512,
      ws + O_BDE, nullptr, 0, 0, 0, 0);
  perm_dec_add<<<32768, 256, 0, stream>>>(Cd, x, x1);

  // ---- inter: LN (permuted, bf16) then chunked bf16-xw GEMM + MFMA LSTM ----
  ln_rows<<<65536, 256, 0, stream>>>(x1, nullptr, z2b, 128, g_in, b_in, nullptr, 1);
  for (int c = 0; c < 8; ++c) {
    gemm_mfma<<<dim3(64, 8), 256, 0, stream>>>(z2b, WihI, xwb, 8192, 1024, 128,
        ws + O_BSI, nullptr, 1, 64, 512, c * 64);
    lstm_inter_mfma<<<8, 512, 0, stream>>>(xwb, WfI, ws + O_HI, ws + O_CI, ysb, c * 64);
  }
  gemm_mfma<<<dim3(512, 1), 256, 0, stream>>>(ysb, WilB, C3, 65536, 128, 256,
      bil, nullptr, 0, 0, 0, 0);
  perm_wil_add<<<32768, 256, 0, stream>>>(C3, x1, dout, doutb);

  // ---- attention projections (QKV fused, N=192, bf16 out) ----
  gemm_mfma<<<dim3(512, 2), 256, 0, stream>>>(doutb, Wqkv, C6, 65536, 192, 128,
      nullptr, nullptr, 1, 0, 0, 0);
  scat_qk<<<16384, 256, 0, stream>>>(C6, bq, bk, aq, ak, Qm, Km);
  scat_v<<<32768, 256, 0, stream>>>(C6, bv, av, Vm);
  ln_rows<<<4096, 256, 0, stream>>>(Qm, Qm, nullptr, 512, gq, bgq, nullptr, 0);
  ln_rows<<<4096, 256, 0, stream>>>(Km, Km, nullptr, 512, gk, bgk, nullptr, 0);
  ln_rows<<<4096, 256, 0, stream>>>(Vm, Vm, nullptr, 2048, gv, bgv, nullptr, 0);

  // ---- banded causal attention ----
  attn_scores<<<dim3(32, 8), 256, 0, stream>>>(Qm, Km, Kbuf, attnw);
  attn_pv<<<dim3(64, 8), 256, 0, stream>>>(attnw, Vm, Vbuf, Vo);

  // ---- output projection + prelu + LN + residual ----
  gather_y<<<32768, 256, 0, stream>>>(Vo, ygb);
  gemm_mfma<<<dim3(512, 1), 256, 0, stream>>>(ygb, WpB, y2, 65536, 128, 128,
      bp, ap, 0, 0, 0, 0);
  ln_rows<<<1024, 256, 0, stream>>>(y2, dout, nullptr, 8192, gp, bgp, dout, 0);
}